// Round 4
// baseline (386.685 us; speedup 1.0000x reference)
//
#include <hip/hip_runtime.h>
#include <hip/hip_bf16.h>
#include <stdint.h>

#define BATCH 16
#define CDIM 1024
#define HWDIM 1024
#define PSTRIDE 2048  // bf16 elements per packed row of the S buffer (4096 B)

typedef __bf16 bf16_t;
typedef short short8 __attribute__((ext_vector_type(8)));
typedef float floatx4 __attribute__((ext_vector_type(4)));

// ---------------------------------------------------------------------------
// GEMM1 (split-precision): S[b][i][j] = sum_k B[b][i][k]*C[b][j][k], f32 in/out.
// Each f32 x -> bf16 hi + bf16 lo; S = hi*hi + hi*lo + lo*hi (3 MFMAs).
// grid (8,8,16), block 256.
// ---------------------------------------------------------------------------
__global__ __launch_bounds__(256) void k_gemm1(const float* __restrict__ Bm,
                                               const float* __restrict__ Cm,
                                               float* __restrict__ S) {
    const int bz = blockIdx.z;
    const int i0 = blockIdx.x * 128;
    const int j0 = blockIdx.y * 128;
    const float* Ap = Bm + (size_t)bz * CDIM * HWDIM;
    const float* Bp = Cm + (size_t)bz * CDIM * HWDIM;
    float* Sp = S + (size_t)bz * CDIM * CDIM;

    __shared__ bf16_t lAhi[128 * 32], lAlo[128 * 32];
    __shared__ bf16_t lBhi[128 * 32], lBlo[128 * 32];

    const int tid = threadIdx.x;
    const int lane = tid & 63;
    const int wave = tid >> 6;
    const int wm = wave >> 1, wn = wave & 1;

    floatx4 acc[4][4];
#pragma unroll
    for (int a = 0; a < 4; ++a)
#pragma unroll
        for (int b = 0; b < 4; ++b) acc[a][b] = (floatx4){0.f, 0.f, 0.f, 0.f};

    const int srow = tid >> 2;        // 0..63
    const int scol = (tid & 3) * 8;   // f32 col {0,8,16,24}
    const int fr = lane & 15;
    const int fk = (lane >> 4) * 8;

    for (int k0 = 0; k0 < HWDIM; k0 += 32) {
#pragma unroll
        for (int p = 0; p < 2; ++p) {
            const int row = p * 64 + srow;
            // ---- A (Bm) ----
            {
                const float* g = Ap + (size_t)(i0 + row) * HWDIM + k0 + scol;
                bf16_t h[8], l[8];
#pragma unroll
                for (int e = 0; e < 8; ++e) {
                    float x = g[e];
                    __bf16 hh = (__bf16)x;
                    h[e] = hh;
                    l[e] = (__bf16)(x - (float)hh);
                }
                *(uint4*)&lAhi[row * 32 + scol] = *(const uint4*)h;
                *(uint4*)&lAlo[row * 32 + scol] = *(const uint4*)l;
            }
            // ---- B (Cm) ----
            {
                const float* g = Bp + (size_t)(j0 + row) * HWDIM + k0 + scol;
                bf16_t h[8], l[8];
#pragma unroll
                for (int e = 0; e < 8; ++e) {
                    float x = g[e];
                    __bf16 hh = (__bf16)x;
                    h[e] = hh;
                    l[e] = (__bf16)(x - (float)hh);
                }
                *(uint4*)&lBhi[row * 32 + scol] = *(const uint4*)h;
                *(uint4*)&lBlo[row * 32 + scol] = *(const uint4*)l;
            }
        }
        __syncthreads();
        short8 ah[4], al[4], bh[4], bl[4];
#pragma unroll
        for (int mt = 0; mt < 4; ++mt) {
            const int off = (wm * 64 + mt * 16 + fr) * 32 + fk;
            ah[mt] = *(const short8*)&lAhi[off];
            al[mt] = *(const short8*)&lAlo[off];
        }
#pragma unroll
        for (int nt = 0; nt < 4; ++nt) {
            const int off = (wn * 64 + nt * 16 + fr) * 32 + fk;
            bh[nt] = *(const short8*)&lBhi[off];
            bl[nt] = *(const short8*)&lBlo[off];
        }
#pragma unroll
        for (int mt = 0; mt < 4; ++mt)
#pragma unroll
            for (int nt = 0; nt < 4; ++nt) {
                acc[mt][nt] = __builtin_amdgcn_mfma_f32_16x16x32_bf16(
                    ah[mt], bh[nt], acc[mt][nt], 0, 0, 0);
                acc[mt][nt] = __builtin_amdgcn_mfma_f32_16x16x32_bf16(
                    ah[mt], bl[nt], acc[mt][nt], 0, 0, 0);
                acc[mt][nt] = __builtin_amdgcn_mfma_f32_16x16x32_bf16(
                    al[mt], bh[nt], acc[mt][nt], 0, 0, 0);
            }
        __syncthreads();
    }

    // D layout: col = lane&15, row = (lane>>4)*4 + reg  [m89/m91-verified]
    const int er = (lane >> 4) * 4;
    const int ec = lane & 15;
#pragma unroll
    for (int mt = 0; mt < 4; ++mt)
#pragma unroll
        for (int nt = 0; nt < 4; ++nt) {
            const int row = i0 + wm * 64 + mt * 16 + er;
            const int col = j0 + wn * 64 + nt * 16 + ec;
            float* dst = Sp + (size_t)row * CDIM + col;
#pragma unroll
            for (int r = 0; r < 4; ++r) dst[(size_t)r * CDIM] = acc[mt][nt][r];
        }
}

// ---------------------------------------------------------------------------
// Softmax over each fp32 row of S (1024); packs P (bf16) into the first
// 2048 B of the row. LDS tree reductions. grid 16384, block 256.
// ---------------------------------------------------------------------------
__global__ __launch_bounds__(256) void k_softmax(float* __restrict__ S) {
    float* rp = S + (size_t)blockIdx.x * CDIM;
    const int tid = threadIdx.x;
    float4 v = ((const float4*)rp)[tid];

    __shared__ float red[256];
    float m = fmaxf(fmaxf(v.x, v.y), fmaxf(v.z, v.w));
    red[tid] = m;
    __syncthreads();
    for (int s = 128; s > 0; s >>= 1) {
        if (tid < s) red[tid] = fmaxf(red[tid], red[tid + s]);
        __syncthreads();
    }
    m = red[0];
    __syncthreads();

    float e0 = __expf(v.x - m), e1 = __expf(v.y - m);
    float e2 = __expf(v.z - m), e3 = __expf(v.w - m);
    red[tid] = e0 + e1 + e2 + e3;
    __syncthreads();
    for (int s = 128; s > 0; s >>= 1) {
        if (tid < s) red[tid] += red[tid + s];
        __syncthreads();
    }
    const float inv = 1.0f / red[0];

    bf16_t p[4];
    p[0] = (__bf16)(e0 * inv);
    p[1] = (__bf16)(e1 * inv);
    p[2] = (__bf16)(e2 * inv);
    p[3] = (__bf16)(e3 * inv);
    ((uint2*)rp)[tid] = *(const uint2*)p;
}

// ---------------------------------------------------------------------------
// Transpose a[b] (C x HW, f32) -> bf16 At rows in the DEAD half of each packed
// S row: At row t at bf16 offset (b*1024 + t)*PSTRIDE + 1024. grid (16,16,16).
// ---------------------------------------------------------------------------
__global__ __launch_bounds__(256) void k_transpose(const float* __restrict__ A,
                                                   bf16_t* __restrict__ SP) {
    const int bz = blockIdx.z;
    const int t0 = blockIdx.x * 64;  // HW block
    const int j0 = blockIdx.y * 64;  // C block
    const float* Ap = A + (size_t)bz * CDIM * HWDIM;
    bf16_t* Atp = SP + (size_t)bz * CDIM * PSTRIDE + 1024;

    __shared__ bf16_t tile[64][68];
    const int lr = threadIdx.x >> 4;         // 0..15
    const int lc = (threadIdx.x & 15) * 4;   // 0..60
#pragma unroll
    for (int r = 0; r < 4; ++r) {
        const float* src = Ap + (size_t)(j0 + lr + r * 16) * HWDIM + t0 + lc;
        float4 f = *(const float4*)src;
        bf16_t t4[4];
        t4[0] = (__bf16)f.x; t4[1] = (__bf16)f.y;
        t4[2] = (__bf16)f.z; t4[3] = (__bf16)f.w;
        *(uint2*)&tile[lr + r * 16][lc] = *(const uint2*)t4;
    }
    __syncthreads();
#pragma unroll
    for (int r = 0; r < 4; ++r) {
        const int trow = lr + r * 16;
        bf16_t tmp[4];
#pragma unroll
        for (int e = 0; e < 4; ++e) tmp[e] = tile[lc + e][trow];
        *(uint2*)(Atp + (size_t)(t0 + trow) * PSTRIDE + j0 + lc) = *(uint2*)tmp;
    }
}

// ---------------------------------------------------------------------------
// GEMM2: Out[b][i][t] = sum_j P[b][i][j]*At[b][t][j] + a[b][i][t] (f32 out).
// P and At both live in the packed S buffer, row stride PSTRIDE bf16.
// grid (8,8,16), block 256.
// ---------------------------------------------------------------------------
__global__ __launch_bounds__(256) void k_gemm2(const bf16_t* __restrict__ SP,
                                               const float* __restrict__ Aorig,
                                               float* __restrict__ Out) {
    const int bz = blockIdx.z;
    const int i0 = blockIdx.x * 128;
    const int t0 = blockIdx.y * 128;
    const bf16_t* Pp = SP + (size_t)bz * CDIM * PSTRIDE;         // P rows
    const bf16_t* Bp = SP + (size_t)bz * CDIM * PSTRIDE + 1024;  // At rows

    __shared__ bf16_t lA[128 * 32];
    __shared__ bf16_t lB[128 * 32];

    const int tid = threadIdx.x;
    const int lane = tid & 63;
    const int wave = tid >> 6;
    const int wm = wave >> 1, wn = wave & 1;

    floatx4 acc[4][4];
#pragma unroll
    for (int a = 0; a < 4; ++a)
#pragma unroll
        for (int b = 0; b < 4; ++b) acc[a][b] = (floatx4){0.f, 0.f, 0.f, 0.f};

    const int srow = tid >> 2;
    const int scol = (tid & 3) * 8;
    const int fr = lane & 15;
    const int fk = (lane >> 4) * 8;

    for (int k0 = 0; k0 < CDIM; k0 += 32) {
        uint4 va[2], vb[2];
#pragma unroll
        for (int p = 0; p < 2; ++p) {
            va[p] = *(const uint4*)(Pp + (size_t)(i0 + p * 64 + srow) * PSTRIDE + k0 + scol);
            vb[p] = *(const uint4*)(Bp + (size_t)(t0 + p * 64 + srow) * PSTRIDE + k0 + scol);
        }
#pragma unroll
        for (int p = 0; p < 2; ++p) {
            *(uint4*)&lA[(p * 64 + srow) * 32 + scol] = va[p];
            *(uint4*)&lB[(p * 64 + srow) * 32 + scol] = vb[p];
        }
        __syncthreads();
        short8 af[4], bfr[4];
#pragma unroll
        for (int mt = 0; mt < 4; ++mt)
            af[mt] = *(const short8*)&lA[(wm * 64 + mt * 16 + fr) * 32 + fk];
#pragma unroll
        for (int nt = 0; nt < 4; ++nt)
            bfr[nt] = *(const short8*)&lB[(wn * 64 + nt * 16 + fr) * 32 + fk];
#pragma unroll
        for (int mt = 0; mt < 4; ++mt)
#pragma unroll
            for (int nt = 0; nt < 4; ++nt)
                acc[mt][nt] = __builtin_amdgcn_mfma_f32_16x16x32_bf16(
                    af[mt], bfr[nt], acc[mt][nt], 0, 0, 0);
        __syncthreads();
    }

    const float* ap = Aorig + (size_t)bz * CDIM * HWDIM;
    float* op = Out + (size_t)bz * CDIM * HWDIM;
    const int er = (lane >> 4) * 4;
    const int ec = lane & 15;
#pragma unroll
    for (int mt = 0; mt < 4; ++mt)
#pragma unroll
        for (int nt = 0; nt < 4; ++nt) {
            const int col = t0 + wn * 64 + nt * 16 + ec;
#pragma unroll
            for (int r = 0; r < 4; ++r) {
                const int row = i0 + wm * 64 + mt * 16 + er + r;
                const size_t idx = (size_t)row * HWDIM + col;
                op[idx] = acc[mt][nt][r] + ap[idx];
            }
        }
}

extern "C" void kernel_launch(void* const* d_in, const int* in_sizes, int n_in,
                              void* d_out, int out_size, void* d_ws, size_t ws_size,
                              hipStream_t stream) {
    const float* a = (const float*)d_in[0];
    const float* b = (const float*)d_in[1];
    const float* c = (const float*)d_in[2];
    float* out = (float*)d_out;

    float* S = (float*)d_ws;  // 64 MB: fp32 scores, then {P | At} packed per row

    k_gemm1<<<dim3(8, 8, 16), 256, 0, stream>>>(b, c, S);
    k_softmax<<<dim3(BATCH * CDIM), 256, 0, stream>>>(S);
    k_transpose<<<dim3(16, 16, 16), 256, 0, stream>>>(a, (bf16_t*)S);
    k_gemm2<<<dim3(8, 8, 16), 256, 0, stream>>>((const bf16_t*)S, a, out);
}

// Round 5
// 355.999 us; speedup vs baseline: 1.0862x; 1.0862x over previous
//
#include <hip/hip_runtime.h>
#include <hip/hip_bf16.h>
#include <stdint.h>

#define BATCH 16
#define CDIM 1024
#define HWDIM 1024
#define PSTRIDE 2048  // fp16 elements per packed row of the S buffer (4096 B)

typedef _Float16 half_t;
typedef _Float16 half8 __attribute__((ext_vector_type(8)));
typedef float floatx4 __attribute__((ext_vector_type(4)));

__device__ static inline void gld_lds16(const half_t* g, half_t* l) {
    __builtin_amdgcn_global_load_lds(
        (__attribute__((address_space(1))) void*)(void*)g,
        (__attribute__((address_space(3))) void*)l, 16, 0, 0);
}

// ---------------------------------------------------------------------------
// Prep: convert b,c (f32) -> fp16 into scratch (d_out reused as scratch).
// grid (8192, 2), block 256; 8 elems/thread, 16 B stores.
// ---------------------------------------------------------------------------
__global__ __launch_bounds__(256) void k_prep(const float* __restrict__ Bm,
                                              const float* __restrict__ Cm,
                                              half_t* __restrict__ dst) {
    const size_t N = (size_t)BATCH * CDIM * HWDIM;
    const float* src = blockIdx.y ? Cm : Bm;
    half_t* d = dst + (size_t)blockIdx.y * N;
    const size_t base = ((size_t)blockIdx.x * 256 + threadIdx.x) * 8;
    float4 f0 = *(const float4*)(src + base);
    float4 f1 = *(const float4*)(src + base + 4);
    half_t h[8];
    h[0] = (half_t)f0.x; h[1] = (half_t)f0.y; h[2] = (half_t)f0.z; h[3] = (half_t)f0.w;
    h[4] = (half_t)f1.x; h[5] = (half_t)f1.y; h[6] = (half_t)f1.z; h[7] = (half_t)f1.w;
    *(uint4*)(d + base) = *(const uint4*)h;
}

// ---------------------------------------------------------------------------
// GEMM1: S[b][i][j] = sum_k bh[b][i][k] * ch[b][j][k]  (NT, fp16 in, f32 out)
// m97 structure: global_load_lds width-16 staging. grid (8,8,16), block 256.
// ---------------------------------------------------------------------------
__global__ __launch_bounds__(256) void k_gemm1(const half_t* __restrict__ Bh,
                                               const half_t* __restrict__ Ch,
                                               float* __restrict__ S) {
    const int bz = blockIdx.z;
    const int i0 = blockIdx.x * 128;
    const int j0 = blockIdx.y * 128;
    const half_t* Ap = Bh + (size_t)bz * CDIM * HWDIM;
    const half_t* Bp = Ch + (size_t)bz * CDIM * HWDIM;
    float* Sp = S + (size_t)bz * CDIM * CDIM;

    __shared__ half_t lA[128 * 32];
    __shared__ half_t lB[128 * 32];

    const int tid = threadIdx.x;
    const int lane = tid & 63;
    const int wave = tid >> 6;
    const int wm = wave >> 1, wn = wave & 1;

    floatx4 acc[4][4];
#pragma unroll
    for (int a = 0; a < 4; ++a)
#pragma unroll
        for (int b = 0; b < 4; ++b) acc[a][b] = (floatx4){0.f, 0.f, 0.f, 0.f};

    const int srow = tid >> 2;        // 0..63
    const int scol = (tid & 3) * 8;   // 0,8,16,24 (fp16 elems; 16 B per lane)
    const int fr = lane & 15;
    const int fk = (lane >> 4) * 8;

    for (int k0 = 0; k0 < HWDIM; k0 += 32) {
#pragma unroll
        for (int p = 0; p < 2; ++p) {
            gld_lds16(Ap + (size_t)(i0 + p * 64 + srow) * HWDIM + k0 + scol,
                      &lA[(p * 64 + srow) * 32 + scol]);
            gld_lds16(Bp + (size_t)(j0 + p * 64 + srow) * HWDIM + k0 + scol,
                      &lB[(p * 64 + srow) * 32 + scol]);
        }
        __syncthreads();
        half8 af[4], bfr[4];
#pragma unroll
        for (int mt = 0; mt < 4; ++mt)
            af[mt] = *(const half8*)&lA[(wm * 64 + mt * 16 + fr) * 32 + fk];
#pragma unroll
        for (int nt = 0; nt < 4; ++nt)
            bfr[nt] = *(const half8*)&lB[(wn * 64 + nt * 16 + fr) * 32 + fk];
#pragma unroll
        for (int mt = 0; mt < 4; ++mt)
#pragma unroll
            for (int nt = 0; nt < 4; ++nt)
                acc[mt][nt] = __builtin_amdgcn_mfma_f32_16x16x32_f16(
                    af[mt], bfr[nt], acc[mt][nt], 0, 0, 0);
        __syncthreads();
    }

    // D layout: col = lane&15, row = (lane>>4)*4 + reg  [m89/m91; dtype-indep]
    const int er = (lane >> 4) * 4;
    const int ec = lane & 15;
#pragma unroll
    for (int mt = 0; mt < 4; ++mt)
#pragma unroll
        for (int nt = 0; nt < 4; ++nt) {
            const int row = i0 + wm * 64 + mt * 16 + er;
            const int col = j0 + wn * 64 + nt * 16 + ec;
            float* dst = Sp + (size_t)row * CDIM + col;
#pragma unroll
            for (int r = 0; r < 4; ++r) dst[(size_t)r * CDIM] = acc[mt][nt][r];
        }
}

// ---------------------------------------------------------------------------
// Softmax over each fp32 row of S (1024); packs P (fp16) into the first
// 2048 B of the row. grid 16384, block 256.
// ---------------------------------------------------------------------------
__global__ __launch_bounds__(256) void k_softmax(float* __restrict__ S) {
    float* rp = S + (size_t)blockIdx.x * CDIM;
    const int tid = threadIdx.x;
    float4 v = ((const float4*)rp)[tid];

    __shared__ float red[256];
    float m = fmaxf(fmaxf(v.x, v.y), fmaxf(v.z, v.w));
    red[tid] = m;
    __syncthreads();
    for (int s = 128; s > 0; s >>= 1) {
        if (tid < s) red[tid] = fmaxf(red[tid], red[tid + s]);
        __syncthreads();
    }
    m = red[0];
    __syncthreads();

    float e0 = __expf(v.x - m), e1 = __expf(v.y - m);
    float e2 = __expf(v.z - m), e3 = __expf(v.w - m);
    red[tid] = e0 + e1 + e2 + e3;
    __syncthreads();
    for (int s = 128; s > 0; s >>= 1) {
        if (tid < s) red[tid] += red[tid + s];
        __syncthreads();
    }
    const float inv = 1.0f / red[0];

    half_t p[4];
    p[0] = (half_t)(e0 * inv);
    p[1] = (half_t)(e1 * inv);
    p[2] = (half_t)(e2 * inv);
    p[3] = (half_t)(e3 * inv);
    ((uint2*)rp)[tid] = *(const uint2*)p;
}

// ---------------------------------------------------------------------------
// Transpose a[b] (C x HW, f32) -> fp16 At rows in the DEAD half of each packed
// S row (offset +1024 fp16). Runs AFTER softmax. grid (16,16,16).
// ---------------------------------------------------------------------------
__global__ __launch_bounds__(256) void k_transpose(const float* __restrict__ A,
                                                   half_t* __restrict__ SP) {
    const int bz = blockIdx.z;
    const int t0 = blockIdx.x * 64;  // HW block
    const int j0 = blockIdx.y * 64;  // C block
    const float* Ap = A + (size_t)bz * CDIM * HWDIM;
    half_t* Atp = SP + (size_t)bz * CDIM * PSTRIDE + 1024;

    __shared__ half_t tile[64][68];
    const int lr = threadIdx.x >> 4;         // 0..15
    const int lc = (threadIdx.x & 15) * 4;   // 0..60
#pragma unroll
    for (int r = 0; r < 4; ++r) {
        const float* src = Ap + (size_t)(j0 + lr + r * 16) * HWDIM + t0 + lc;
        float4 f = *(const float4*)src;
        half_t t4[4];
        t4[0] = (half_t)f.x; t4[1] = (half_t)f.y;
        t4[2] = (half_t)f.z; t4[3] = (half_t)f.w;
        *(uint2*)&tile[lr + r * 16][lc] = *(const uint2*)t4;
    }
    __syncthreads();
#pragma unroll
    for (int r = 0; r < 4; ++r) {
        const int trow = lr + r * 16;
        half_t tmp[4];
#pragma unroll
        for (int e = 0; e < 4; ++e) tmp[e] = tile[lc + e][trow];
        *(uint2*)(Atp + (size_t)(t0 + trow) * PSTRIDE + j0 + lc) = *(uint2*)tmp;
    }
}

// ---------------------------------------------------------------------------
// GEMM2: Out[b][i][t] = sum_j P[b][i][j]*At[b][t][j] + a[b][i][t] (f32 out).
// P and At (fp16) both live in the packed S buffer, row stride PSTRIDE.
// grid (8,8,16), block 256.
// ---------------------------------------------------------------------------
__global__ __launch_bounds__(256) void k_gemm2(const half_t* __restrict__ SP,
                                               const float* __restrict__ Aorig,
                                               float* __restrict__ Out) {
    const int bz = blockIdx.z;
    const int i0 = blockIdx.x * 128;
    const int t0 = blockIdx.y * 128;
    const half_t* Pp = SP + (size_t)bz * CDIM * PSTRIDE;         // P rows
    const half_t* Bp = SP + (size_t)bz * CDIM * PSTRIDE + 1024;  // At rows

    __shared__ half_t lA[128 * 32];
    __shared__ half_t lB[128 * 32];

    const int tid = threadIdx.x;
    const int lane = tid & 63;
    const int wave = tid >> 6;
    const int wm = wave >> 1, wn = wave & 1;

    floatx4 acc[4][4];
#pragma unroll
    for (int a = 0; a < 4; ++a)
#pragma unroll
        for (int b = 0; b < 4; ++b) acc[a][b] = (floatx4){0.f, 0.f, 0.f, 0.f};

    const int srow = tid >> 2;
    const int scol = (tid & 3) * 8;
    const int fr = lane & 15;
    const int fk = (lane >> 4) * 8;

    for (int k0 = 0; k0 < CDIM; k0 += 32) {
#pragma unroll
        for (int p = 0; p < 2; ++p) {
            gld_lds16(Pp + (size_t)(i0 + p * 64 + srow) * PSTRIDE + k0 + scol,
                      &lA[(p * 64 + srow) * 32 + scol]);
            gld_lds16(Bp + (size_t)(t0 + p * 64 + srow) * PSTRIDE + k0 + scol,
                      &lB[(p * 64 + srow) * 32 + scol]);
        }
        __syncthreads();
        half8 af[4], bfr[4];
#pragma unroll
        for (int mt = 0; mt < 4; ++mt)
            af[mt] = *(const half8*)&lA[(wm * 64 + mt * 16 + fr) * 32 + fk];
#pragma unroll
        for (int nt = 0; nt < 4; ++nt)
            bfr[nt] = *(const half8*)&lB[(wn * 64 + nt * 16 + fr) * 32 + fk];
#pragma unroll
        for (int mt = 0; mt < 4; ++mt)
#pragma unroll
            for (int nt = 0; nt < 4; ++nt)
                acc[mt][nt] = __builtin_amdgcn_mfma_f32_16x16x32_f16(
                    af[mt], bfr[nt], acc[mt][nt], 0, 0, 0);
        __syncthreads();
    }

    const float* ap = Aorig + (size_t)bz * CDIM * HWDIM;
    float* op = Out + (size_t)bz * CDIM * HWDIM;
    const int er = (lane >> 4) * 4;
    const int ec = lane & 15;
#pragma unroll
    for (int mt = 0; mt < 4; ++mt)
#pragma unroll
        for (int nt = 0; nt < 4; ++nt) {
            const int col = t0 + wn * 64 + nt * 16 + ec;
#pragma unroll
            for (int r = 0; r < 4; ++r) {
                const int row = i0 + wm * 64 + mt * 16 + er + r;
                const size_t idx = (size_t)row * HWDIM + col;
                op[idx] = acc[mt][nt][r] + ap[idx];
            }
        }
}

extern "C" void kernel_launch(void* const* d_in, const int* in_sizes, int n_in,
                              void* d_out, int out_size, void* d_ws, size_t ws_size,
                              hipStream_t stream) {
    const float* a = (const float*)d_in[0];
    const float* b = (const float*)d_in[1];
    const float* c = (const float*)d_in[2];
    float* out = (float*)d_out;

    float* S = (float*)d_ws;            // 64 MB: fp32 scores -> {P | At} packed
    half_t* bc16 = (half_t*)d_out;      // d_out doubles as fp16 scratch for b,c
                                        // (gemm2 fully overwrites it at the end)

    k_prep<<<dim3(8192, 2), 256, 0, stream>>>(b, c, bc16);
    k_gemm1<<<dim3(8, 8, 16), 256, 0, stream>>>(
        bc16, bc16 + (size_t)BATCH * CDIM * HWDIM, S);
    k_softmax<<<dim3(BATCH * CDIM), 256, 0, stream>>>(S);
    k_transpose<<<dim3(16, 16, 16), 256, 0, stream>>>(a, (half_t*)S);
    k_gemm2<<<dim3(8, 8, 16), 256, 0, stream>>>((const half_t*)S, a, out);
}